// Round 3
// baseline (768.115 us; speedup 1.0000x reference)
//
#include <hip/hip_runtime.h>
#include <hip/hip_bf16.h>
#include <stdint.h>

// ContextEmbedding: Q/K/V proj -> 16-head cross-attention (N1=256 q, N2=4096
// kv, d=64) -> P proj -> row L2-normalize -> concat([E, U]).
//
// Round 3: environment-robust version. Two unverified assumptions could
// explain rounds 1-2 NaN with verified index math: (a) input dtype (ref file
// says f32, test label says bf16), (b) ws_size < 136 MB (OOB scratch writes).
// This round: runtime dtype detection + dual pipelines with device-side
// early-out; ws_size-adaptive head grouping (G in {16,8,4,2}, needs 5+8G MB);
// U in-place over Q; clamps that turn any garbage into finite diagnostics.

typedef __bf16 bf16_t;
typedef __attribute__((ext_vector_type(8))) __bf16 bf16x8;
typedef __attribute__((ext_vector_type(4))) float f32x4;

#define DEVINL __device__ __forceinline__

DEVINL f32x4 mfma16(bf16x8 a, bf16x8 b, f32x4 c) {
  return __builtin_amdgcn_mfma_f32_16x16x32_bf16(a, b, c, 0, 0, 0);
}

DEVINL bf16x8 load8(const bf16_t* p) { return *(const bf16x8*)p; }
DEVINL bf16x8 load8(const float* p) {
  const float4 u = *(const float4*)p;
  const float4 v = *(const float4*)(p + 4);
  bf16x8 r;
  r[0] = (bf16_t)u.x; r[1] = (bf16_t)u.y; r[2] = (bf16_t)u.z; r[3] = (bf16_t)u.w;
  r[4] = (bf16_t)v.x; r[5] = (bf16_t)v.y; r[6] = (bf16_t)v.z; r[7] = (bf16_t)v.w;
  return r;
}

// If inputs are f32, even-indexed bf16 reinterpretations are low-mantissa
// bits with uniform exponents -> some |x| >> 100 (or inf/NaN) almost surely.
// If genuinely bf16 (E ~ N(0,1)), all |x| < ~6. flag: 1 = bf16, 0 = f32.
__global__ void detect_dtype(const bf16_t* __restrict__ e, int* __restrict__ flag) {
  __shared__ int bad_s;
  if (threadIdx.x == 0) bad_s = 0;
  __syncthreads();
  int bad = 0;
  for (int i = threadIdx.x; i < 4096; i += 256) {
    const float v = fabsf((float)e[2 * i]);
    if (!(v < 100.0f)) bad = 1;  // catches huge, inf, NaN
  }
  if (bad) bad_s = 1;
  __syncthreads();
  if (threadIdx.x == 0) *flag = bad_s ? 0 : 1;
}

// C[M,N] = A[M,K] @ B[N,K]^T + bias. 128x128 tile, BK=32, XOR chunk swizzle.
// MODE 0: bf16 out, bias[n]; MODE 1: bf16 out, bias[m]; MODE 2: f32 out, bias[n]
template <int MODE, typename TA, typename TB>
__global__ __launch_bounds__(256) void gemm_bt(
    const int* __restrict__ flag, int expect,
    const TA* __restrict__ A, const TB* __restrict__ B,
    const TB* __restrict__ bias, void* __restrict__ Cv,
    int M, int N, int K) {
  if (*flag != expect) return;
  __shared__ bf16_t As[128 * 32];
  __shared__ bf16_t Bs[128 * 32];
  const int tid = threadIdx.x;
  const int w = tid >> 6, lane = tid & 63, quad = lane >> 4, l16 = lane & 15;
  const int bm = blockIdx.x * 128, bn = blockIdx.y * 128;
  const int wm = (w & 1) * 64, wn = (w >> 1) * 64;

  // row r phys chunk p holds logical k-chunk p^(r&3); frag read at quad^(r&3)
  const int srow = tid >> 2;
  const int swz = ((tid & 3) ^ (srow & 3)) * 8;

  const TA* Ag0 = A + (size_t)(bm + srow) * K + swz;
  const TA* Ag1 = Ag0 + (size_t)64 * K;
  const TB* Bg0 = B + (size_t)(bn + srow) * K + swz;
  const TB* Bg1 = Bg0 + (size_t)64 * K;
  bf16_t* Al0 = As + tid * 8;
  bf16_t* Al1 = As + 64 * 32 + tid * 8;
  bf16_t* Bl0 = Bs + tid * 8;
  bf16_t* Bl1 = Bs + 64 * 32 + tid * 8;

  f32x4 acc[4][4] = {};

  for (int k0 = 0; k0 < K; k0 += 32) {
    const bf16x8 a0 = load8(Ag0 + k0);
    const bf16x8 a1 = load8(Ag1 + k0);
    const bf16x8 b0 = load8(Bg0 + k0);
    const bf16x8 b1 = load8(Bg1 + k0);
    *(bf16x8*)Al0 = a0;
    *(bf16x8*)Al1 = a1;
    *(bf16x8*)Bl0 = b0;
    *(bf16x8*)Bl1 = b1;
    __syncthreads();
    bf16x8 af[4], bfr[4];
#pragma unroll
    for (int mt = 0; mt < 4; mt++) {
      const int r = wm + mt * 16 + l16;
      af[mt] = *(const bf16x8*)(As + r * 32 + ((quad ^ (r & 3)) * 8));
    }
#pragma unroll
    for (int nt = 0; nt < 4; nt++) {
      const int r = wn + nt * 16 + l16;
      bfr[nt] = *(const bf16x8*)(Bs + r * 32 + ((quad ^ (r & 3)) * 8));
    }
#pragma unroll
    for (int mt = 0; mt < 4; mt++)
#pragma unroll
      for (int nt = 0; nt < 4; nt++)
        acc[mt][nt] = mfma16(af[mt], bfr[nt], acc[mt][nt]);
    __syncthreads();
  }

#pragma unroll
  for (int mt = 0; mt < 4; mt++) {
#pragma unroll
    for (int nt = 0; nt < 4; nt++) {
      const int gm0 = bm + wm + mt * 16 + quad * 4;
      const int gn = bn + wn + nt * 16 + l16;
#pragma unroll
      for (int r = 0; r < 4; r++) {
        const int gm = gm0 + r;
        float v = acc[mt][nt][r] + (float)bias[MODE == 1 ? gm : gn];
        if (MODE == 2)
          ((float*)Cv)[(size_t)gm * N + gn] = v;
        else
          ((bf16_t*)Cv)[(size_t)gm * N + gn] = (bf16_t)v;
      }
    }
  }
}

// Flash cross-attention for head-group [hg, hg+G). QU: Q read / U written
// in-place (each block touches only its own rows x head-dims; Q is loaded to
// registers before any U write). Kbuf [32768, Kst], Vtbuf [Kst, 32768].
__global__ __launch_bounds__(256) void attn_kernel(
    const int* __restrict__ flag, int expect, bf16_t* QU,
    const bf16_t* __restrict__ Kbuf, const bf16_t* __restrict__ Vtbuf,
    int hg, int Kst) {
  if (*flag != expect) return;
  __shared__ bf16_t Ks[64 * 64];
  __shared__ bf16_t Vs[64 * 64];
  __shared__ bf16_t Ps[4][16 * 64];
  const int tid = threadIdx.x;
  const int w = tid >> 6, lane = tid & 63, quad = lane >> 4, l16 = lane & 15;
  const int qt = blockIdx.x, hh = blockIdx.y, b = blockIdx.z;
  const int h = hg + hh;

  const int qrow = b * 256 + qt * 64 + w * 16 + l16;
  const bf16_t* qbase = QU + (size_t)qrow * 1024 + h * 64 + quad * 8;
  const bf16x8 qf0 = *(const bf16x8*)(qbase);
  const bf16x8 qf1 = *(const bf16x8*)(qbase + 32);

  const int srow = tid >> 3;
  const int swz = ((tid & 7) ^ (srow & 7)) * 8;
  const bf16_t* Kg = Kbuf + (size_t)(b * 4096 + srow) * Kst + hh * 64 + swz;
  const bf16_t* Vg = Vtbuf + (size_t)(hh * 64 + srow) * 32768 + b * 4096 + swz;

  f32x4 o[4] = {};
  float mrow[4] = {-1e30f, -1e30f, -1e30f, -1e30f};
  float lrow[4] = {0.f, 0.f, 0.f, 0.f};
  const float L2E = 1.4426950408889634f;

  for (int kt = 0; kt < 64; kt++) {
    const bf16x8 kv0 = *(const bf16x8*)(Kg + (size_t)(kt * 64) * Kst);
    const bf16x8 kv1 = *(const bf16x8*)(Kg + (size_t)(kt * 64 + 32) * Kst);
    const bf16x8 vv0 = *(const bf16x8*)(Vg + kt * 64);
    const bf16x8 vv1 = *(const bf16x8*)(Vg + kt * 64 + (size_t)32 * 32768);
    *(bf16x8*)(Ks + tid * 8) = kv0;
    *(bf16x8*)(Ks + 32 * 64 + tid * 8) = kv1;
    *(bf16x8*)(Vs + tid * 8) = vv0;
    *(bf16x8*)(Vs + 32 * 64 + tid * 8) = vv1;
    __syncthreads();

    f32x4 s[4];
#pragma unroll
    for (int nt = 0; nt < 4; nt++) {
      const int key = nt * 16 + l16;
      const bf16x8 kf0 = *(const bf16x8*)(Ks + key * 64 + ((quad ^ (key & 7)) * 8));
      const bf16x8 kf1 = *(const bf16x8*)(Ks + key * 64 + (((quad + 4) ^ (key & 7)) * 8));
      f32x4 z = {0.f, 0.f, 0.f, 0.f};
      z = mfma16(qf0, kf0, z);
      s[nt] = mfma16(qf1, kf1, z);
      // diagnostic clamp: inert on sane data (|s| <= ~25), keeps garbage finite
#pragma unroll
      for (int r = 0; r < 4; r++) {
        float x = s[nt][r];
        x = fminf(fmaxf(x, -80.f), 80.f);
        s[nt][r] = (x == x) ? x : -80.f;
      }
    }

    float mnew[4], alpha[4], rsum[4];
#pragma unroll
    for (int r = 0; r < 4; r++) {
      float mx = fmaxf(fmaxf(s[0][r], s[1][r]), fmaxf(s[2][r], s[3][r]));
      mx = fmaxf(mx, __shfl_xor(mx, 1));
      mx = fmaxf(mx, __shfl_xor(mx, 2));
      mx = fmaxf(mx, __shfl_xor(mx, 4));
      mx = fmaxf(mx, __shfl_xor(mx, 8));
      mnew[r] = fmaxf(mrow[r], mx);
      alpha[r] = exp2f((mrow[r] - mnew[r]) * L2E);
      rsum[r] = 0.f;
    }
#pragma unroll
    for (int nt = 0; nt < 4; nt++) {
      const int key = nt * 16 + l16;
#pragma unroll
      for (int r = 0; r < 4; r++) {
        const float p = exp2f((s[nt][r] - mnew[r]) * L2E);
        rsum[r] += p;
        const int q = quad * 4 + r;
        Ps[w][q * 64 + (((key >> 3) ^ (q & 7)) * 8) + (key & 7)] = (bf16_t)p;
      }
    }
#pragma unroll
    for (int r = 0; r < 4; r++) {
      rsum[r] += __shfl_xor(rsum[r], 1);
      rsum[r] += __shfl_xor(rsum[r], 2);
      rsum[r] += __shfl_xor(rsum[r], 4);
      rsum[r] += __shfl_xor(rsum[r], 8);
      lrow[r] = lrow[r] * alpha[r] + rsum[r];
      mrow[r] = mnew[r];
    }
#pragma unroll
    for (int nt = 0; nt < 4; nt++) {
      o[nt][0] *= alpha[0]; o[nt][1] *= alpha[1];
      o[nt][2] *= alpha[2]; o[nt][3] *= alpha[3];
    }

    __syncthreads();  // Ps visible before frag reads

    const bf16x8 pf0 = *(const bf16x8*)(&Ps[w][l16 * 64 + ((quad ^ (l16 & 7)) * 8)]);
    const bf16x8 pf1 = *(const bf16x8*)(&Ps[w][l16 * 64 + (((quad + 4) ^ (l16 & 7)) * 8)]);
#pragma unroll
    for (int nt = 0; nt < 4; nt++) {
      const int d = nt * 16 + l16;
      const bf16x8 vf0 = *(const bf16x8*)(Vs + d * 64 + ((quad ^ (d & 7)) * 8));
      const bf16x8 vf1 = *(const bf16x8*)(Vs + d * 64 + (((quad + 4) ^ (d & 7)) * 8));
      o[nt] = mfma16(pf0, vf0, o[nt]);
      o[nt] = mfma16(pf1, vf1, o[nt]);
    }
    __syncthreads();  // Ks/Vs/Ps reads done before next staging
  }

  float inv[4];
#pragma unroll
  for (int r = 0; r < 4; r++) inv[r] = 1.0f / fmaxf(lrow[r], 1e-30f);
#pragma unroll
  for (int nt = 0; nt < 4; nt++) {
#pragma unroll
    for (int r = 0; r < 4; r++) {
      const int row = b * 256 + qt * 64 + w * 16 + quad * 4 + r;
      QU[(size_t)row * 1024 + h * 64 + nt * 16 + l16] = (bf16_t)(o[nt][r] * inv[r]);
    }
  }
}

// out = concat([E, P / ||P||_row], -1); output dtype matches TE.
template <typename TE>
__global__ __launch_bounds__(256) void norm_concat(
    const int* __restrict__ flag, int expect,
    const TE* __restrict__ E, const float* __restrict__ P, void* __restrict__ outv) {
  if (*flag != expect) return;
  const int row = blockIdx.x, tid = threadIdx.x;
  const int w = tid >> 6, lane = tid & 63;
  TE* out = (TE*)outv;

  // E passthrough into out[:, 0:1024] (exact: same dtype)
  {
    const TE* ep = E + (size_t)row * 1024 + tid * 4;
    TE* op = out + (size_t)row * 2048 + tid * 4;
    op[0] = ep[0]; op[1] = ep[1]; op[2] = ep[2]; op[3] = ep[3];
  }

  const float4 p = *(const float4*)(P + (size_t)row * 1024 + tid * 4);
  float ss = p.x * p.x + p.y * p.y + p.z * p.z + p.w * p.w;
#pragma unroll
  for (int m = 1; m <= 32; m <<= 1) ss += __shfl_xor(ss, m);
  __shared__ float red[4];
  if (lane == 0) red[w] = ss;
  __syncthreads();
  const float rn = rsqrtf(fmaxf(red[0] + red[1] + red[2] + red[3], 1e-30f));
  TE* op = out + (size_t)row * 2048 + 1024 + tid * 4;
  op[0] = (TE)(p.x * rn);
  op[1] = (TE)(p.y * rn);
  op[2] = (TE)(p.z * rn);
  op[3] = (TE)(p.w * rn);
}

template <typename T>
static void launch_pipeline(const int* flag, int expect, void* const* d_in,
                            bf16_t* QU, bf16_t* Kbuf, bf16_t* Vtbuf, float* Pf,
                            void* d_out, int G, hipStream_t stream) {
  const T* E   = (const T*)d_in[0];
  const T* I   = (const T*)d_in[1];
  const T* q_w = (const T*)d_in[2];
  const T* q_b = (const T*)d_in[3];
  const T* k_w = (const T*)d_in[4];
  const T* k_b = (const T*)d_in[5];
  const T* v_w = (const T*)d_in[6];
  const T* v_b = (const T*)d_in[7];
  const T* p_w = (const T*)d_in[8];
  const T* p_b = (const T*)d_in[9];

  // Q = E @ q_w^T + q_b  -> QU [2048,1024]
  gemm_bt<0, T, T><<<dim3(16, 8), 256, 0, stream>>>(
      flag, expect, E, q_w, q_b, QU, 2048, 1024, 1024);
  for (int hg = 0; hg < 16; hg += G) {
    const int Nh = G * 64;
    // K slice = I @ k_w[hg*64 : hg*64+Nh]^T  -> [32768, Nh]
    gemm_bt<0, T, T><<<dim3(256, Nh / 128), 256, 0, stream>>>(
        flag, expect, I, k_w + (size_t)hg * 64 * 1024, k_b + hg * 64,
        Kbuf, 32768, Nh, 1024);
    // Vt slice = v_w[rows] @ I^T  -> [Nh, 32768] (bias over rows)
    gemm_bt<1, T, T><<<dim3(Nh / 128, 256), 256, 0, stream>>>(
        flag, expect, v_w + (size_t)hg * 64 * 1024, I, v_b + hg * 64,
        Vtbuf, Nh, 32768, 1024);
    attn_kernel<<<dim3(4, G, 8), 256, 0, stream>>>(
        flag, expect, QU, Kbuf, Vtbuf, hg, Nh);
  }
  // P = U @ p_w^T + p_b (U lives in QU; f32 out for the normalize)
  gemm_bt<2, bf16_t, T><<<dim3(16, 8), 256, 0, stream>>>(
      flag, expect, QU, p_w, p_b, Pf, 2048, 1024, 1024);
  norm_concat<T><<<2048, 256, 0, stream>>>(flag, expect, E, Pf, d_out);
}

extern "C" void kernel_launch(void* const* d_in, const int* in_sizes, int n_in,
                              void* d_out, int out_size, void* d_ws, size_t ws_size,
                              hipStream_t stream) {
  (void)in_sizes; (void)n_in; (void)out_size;
  char* ws = (char*)d_ws;
  int* flag = (int*)ws;
  bf16_t* QU = (bf16_t*)(ws + (1u << 20));      // 4 MB
  bf16_t* Kbuf = (bf16_t*)(ws + (5u << 20));    // G*4 MB
  float* Pf = (float*)(ws + (5u << 20));        // 8 MB, overlays Kbuf (dead)

  // need 5 + 8G MB of scratch
  int G = 2;
  if (ws_size >= (133ull << 20)) G = 16;
  else if (ws_size >= (69ull << 20)) G = 8;
  else if (ws_size >= (37ull << 20)) G = 4;
  bf16_t* Vtbuf = (bf16_t*)(ws + (5u << 20) + ((size_t)G << 22));

  detect_dtype<<<1, 256, 0, stream>>>((const bf16_t*)d_in[0], flag);
  launch_pipeline<bf16_t>(flag, 1, d_in, QU, Kbuf, Vtbuf, Pf, d_out, G, stream);
  launch_pipeline<float>(flag, 0, d_in, QU, Kbuf, Vtbuf, Pf, d_out, G, stream);
}

// Round 4
// 641.111 us; speedup vs baseline: 1.1981x; 1.1981x over previous
//
#include <hip/hip_runtime.h>
#include <hip/hip_bf16.h>
#include <stdint.h>

// ContextEmbedding (f32 I/O, proven round 3): Q/K/V proj -> 16-head cross
// attention (N1=256 q, N2=4096 kv, d=64) -> P proj -> L2-normalize ->
// concat([E, U]).  ~183 GF, MFMA-bound.
//
// Round 4:
//  - inputs/output hardcoded f32 (round-2 vs round-3 bisection proof).
//  - big GEMMs: one-time f32->bf16 conversion, then global_load_lds(16B)
//    m97-pattern GEMM (874 TF measured) when ws_size >= 200 MB; otherwise
//    the proven round-3 register-staged path (ws >= 133 MB proven).
//  - attn: register prefetch of next K/V tile (hides HBM latency behind the
//    compute phase; index math identical) + XCD swizzle (qt-siblings of one
//    (h,b) share an XCD L2 -> K/V slice fetched once per XCD).

typedef __bf16 bf16_t;
typedef __attribute__((ext_vector_type(8))) __bf16 bf16x8;
typedef __attribute__((ext_vector_type(4))) float f32x4;

#define DEVINL __device__ __forceinline__

DEVINL f32x4 mfma16(bf16x8 a, bf16x8 b, f32x4 c) {
  return __builtin_amdgcn_mfma_f32_16x16x32_bf16(a, b, c, 0, 0, 0);
}

DEVINL bf16x8 load8(const bf16_t* p) { return *(const bf16x8*)p; }
DEVINL bf16x8 load8(const float* p) {
  const float4 u = *(const float4*)p;
  const float4 v = *(const float4*)(p + 4);
  bf16x8 r;
  r[0] = (bf16_t)u.x; r[1] = (bf16_t)u.y; r[2] = (bf16_t)u.z; r[3] = (bf16_t)u.w;
  r[4] = (bf16_t)v.x; r[5] = (bf16_t)v.y; r[6] = (bf16_t)v.z; r[7] = (bf16_t)v.w;
  return r;
}

// async global->LDS, 16 B per lane. LDS dest must be wave-uniform base +
// lane*16 (it is: we always pass base + tid*16B). Low 32 bits of a generic
// LDS pointer are the LDS offset on gfx9+.
DEVINL void async16(const void* g, void* l) {
  typedef const __attribute__((address_space(1))) unsigned int* gp1;
  typedef __attribute__((address_space(3))) unsigned int* lp3;
  __builtin_amdgcn_global_load_lds((gp1)(uintptr_t)g,
                                   (lp3)(uint32_t)(uintptr_t)l, 16, 0, 0);
}

__global__ __launch_bounds__(256) void cvt_f32_bf16(
    const float* __restrict__ src, bf16_t* __restrict__ dst, int n8) {
  const int i = blockIdx.x * 256 + threadIdx.x;
  if (i < n8) *(bf16x8*)(dst + (size_t)i * 8) = load8(src + (size_t)i * 8);
}

// ---- m97-pattern async GEMM: C[M,N] = A[M,K] @ B[N,K]^T + bias (bf16 in).
// MODE 0: bf16 out, bias[n]; MODE 1: bf16 out, bias[m].
template <int MODE>
__global__ __launch_bounds__(256) void gemm_bt_async(
    const bf16_t* __restrict__ A, const bf16_t* __restrict__ B,
    const float* __restrict__ bias, bf16_t* __restrict__ C,
    int M, int N, int K) {
  __shared__ bf16_t As[128 * 32];
  __shared__ bf16_t Bs[128 * 32];
  const int tid = threadIdx.x;
  const int w = tid >> 6, lane = tid & 63, quad = lane >> 4, l16 = lane & 15;
  const int bm = blockIdx.x * 128, bn = blockIdx.y * 128;
  const int wm = (w & 1) * 64, wn = (w >> 1) * 64;

  // row r phys chunk p holds logical k-chunk p^(r&3); frag read at quad^(r&3)
  const int srow = tid >> 2;
  const int swz = ((tid & 3) ^ (srow & 3)) * 8;

  const bf16_t* Ag0 = A + (size_t)(bm + srow) * K + swz;
  const bf16_t* Ag1 = Ag0 + (size_t)64 * K;
  const bf16_t* Bg0 = B + (size_t)(bn + srow) * K + swz;
  const bf16_t* Bg1 = Bg0 + (size_t)64 * K;
  bf16_t* Al0 = As + tid * 8;
  bf16_t* Al1 = As + 64 * 32 + tid * 8;
  bf16_t* Bl0 = Bs + tid * 8;
  bf16_t* Bl1 = Bs + 64 * 32 + tid * 8;

  f32x4 acc[4][4] = {};

  for (int k0 = 0; k0 < K; k0 += 32) {
    async16(Ag0 + k0, Al0);
    async16(Ag1 + k0, Al1);
    async16(Bg0 + k0, Bl0);
    async16(Bg1 + k0, Bl1);
    __syncthreads();  // vmcnt(0) drain + barrier: staged tile visible
    bf16x8 af[4], bfr[4];
#pragma unroll
    for (int mt = 0; mt < 4; mt++) {
      const int r = wm + mt * 16 + l16;
      af[mt] = *(const bf16x8*)(As + r * 32 + ((quad ^ (r & 3)) * 8));
    }
#pragma unroll
    for (int nt = 0; nt < 4; nt++) {
      const int r = wn + nt * 16 + l16;
      bfr[nt] = *(const bf16x8*)(Bs + r * 32 + ((quad ^ (r & 3)) * 8));
    }
#pragma unroll
    for (int mt = 0; mt < 4; mt++)
#pragma unroll
      for (int nt = 0; nt < 4; nt++)
        acc[mt][nt] = mfma16(af[mt], bfr[nt], acc[mt][nt]);
    __syncthreads();
  }

#pragma unroll
  for (int mt = 0; mt < 4; mt++) {
#pragma unroll
    for (int nt = 0; nt < 4; nt++) {
      const int gm0 = bm + wm + mt * 16 + quad * 4;
      const int gn = bn + wn + nt * 16 + l16;
#pragma unroll
      for (int r = 0; r < 4; r++) {
        const int gm = gm0 + r;
        C[(size_t)gm * N + gn] =
            (bf16_t)(acc[mt][nt][r] + bias[MODE == 1 ? gm : gn]);
      }
    }
  }
}

// ---- round-3 proven register-staged GEMM (small GEMMs + low-ws fallback).
// MODE 0: bf16 out, bias[n]; MODE 1: bf16 out, bias[m]; MODE 2: f32 out, bias[n]
template <int MODE, typename TA, typename TB>
__global__ __launch_bounds__(256) void gemm_bt_reg(
    const TA* __restrict__ A, const TB* __restrict__ B,
    const float* __restrict__ bias, void* __restrict__ Cv,
    int M, int N, int K) {
  __shared__ bf16_t As[128 * 32];
  __shared__ bf16_t Bs[128 * 32];
  const int tid = threadIdx.x;
  const int w = tid >> 6, lane = tid & 63, quad = lane >> 4, l16 = lane & 15;
  const int bm = blockIdx.x * 128, bn = blockIdx.y * 128;
  const int wm = (w & 1) * 64, wn = (w >> 1) * 64;

  const int srow = tid >> 2;
  const int swz = ((tid & 3) ^ (srow & 3)) * 8;

  const TA* Ag0 = A + (size_t)(bm + srow) * K + swz;
  const TA* Ag1 = Ag0 + (size_t)64 * K;
  const TB* Bg0 = B + (size_t)(bn + srow) * K + swz;
  const TB* Bg1 = Bg0 + (size_t)64 * K;
  bf16_t* Al0 = As + tid * 8;
  bf16_t* Al1 = As + 64 * 32 + tid * 8;
  bf16_t* Bl0 = Bs + tid * 8;
  bf16_t* Bl1 = Bs + 64 * 32 + tid * 8;

  f32x4 acc[4][4] = {};

  for (int k0 = 0; k0 < K; k0 += 32) {
    const bf16x8 a0 = load8(Ag0 + k0);
    const bf16x8 a1 = load8(Ag1 + k0);
    const bf16x8 b0 = load8(Bg0 + k0);
    const bf16x8 b1 = load8(Bg1 + k0);
    *(bf16x8*)Al0 = a0;
    *(bf16x8*)Al1 = a1;
    *(bf16x8*)Bl0 = b0;
    *(bf16x8*)Bl1 = b1;
    __syncthreads();
    bf16x8 af[4], bfr[4];
#pragma unroll
    for (int mt = 0; mt < 4; mt++) {
      const int r = wm + mt * 16 + l16;
      af[mt] = *(const bf16x8*)(As + r * 32 + ((quad ^ (r & 3)) * 8));
    }
#pragma unroll
    for (int nt = 0; nt < 4; nt++) {
      const int r = wn + nt * 16 + l16;
      bfr[nt] = *(const bf16x8*)(Bs + r * 32 + ((quad ^ (r & 3)) * 8));
    }
#pragma unroll
    for (int mt = 0; mt < 4; mt++)
#pragma unroll
      for (int nt = 0; nt < 4; nt++)
        acc[mt][nt] = mfma16(af[mt], bfr[nt], acc[mt][nt]);
    __syncthreads();
  }

#pragma unroll
  for (int mt = 0; mt < 4; mt++) {
#pragma unroll
    for (int nt = 0; nt < 4; nt++) {
      const int gm0 = bm + wm + mt * 16 + quad * 4;
      const int gn = bn + wn + nt * 16 + l16;
#pragma unroll
      for (int r = 0; r < 4; r++) {
        const int gm = gm0 + r;
        float v = acc[mt][nt][r] + bias[MODE == 1 ? gm : gn];
        if (MODE == 2)
          ((float*)Cv)[(size_t)gm * N + gn] = v;
        else
          ((bf16_t*)Cv)[(size_t)gm * N + gn] = (bf16_t)v;
      }
    }
  }
}

// ---- flash cross-attention with register prefetch + XCD swizzle.
// grid = 32*G blocks (1-D). Block flat id: qt = id/(8G) -> qt-siblings of one
// (h,b) are spaced 8G apart == same id mod 8 == same XCD.
__global__ __launch_bounds__(256) void attn_kernel(
    bf16_t* QU, const bf16_t* __restrict__ Kbuf,
    const bf16_t* __restrict__ Vtbuf, int hg, int G, int Kst) {
  __shared__ bf16_t Ks[64 * 64];
  __shared__ bf16_t Vs[64 * 64];
  __shared__ bf16_t Ps[4][16 * 64];
  const int tid = threadIdx.x;
  const int w = tid >> 6, lane = tid & 63, quad = lane >> 4, l16 = lane & 15;
  const int flat = blockIdx.x;
  const int qt = flat / (8 * G);
  const int rem = flat - qt * 8 * G;
  const int hh = rem % G, b = rem / G;
  const int h = hg + hh;

  const int qrow = b * 256 + qt * 64 + w * 16 + l16;
  const bf16_t* qbase = QU + (size_t)qrow * 1024 + h * 64 + quad * 8;
  const bf16x8 qf0 = *(const bf16x8*)(qbase);
  const bf16x8 qf1 = *(const bf16x8*)(qbase + 32);

  const int srow = tid >> 3;
  const int swz = ((tid & 7) ^ (srow & 7)) * 8;
  const bf16_t* Kg = Kbuf + (size_t)(b * 4096 + srow) * Kst + hh * 64 + swz;
  const bf16_t* Vg = Vtbuf + (size_t)(hh * 64 + srow) * 32768 + b * 4096 + swz;

  f32x4 o[4] = {};
  float mrow[4] = {-1e30f, -1e30f, -1e30f, -1e30f};
  float lrow[4] = {0.f, 0.f, 0.f, 0.f};
  const float L2E = 1.4426950408889634f;

  // prefetch tile 0 into registers
  bf16x8 kv0 = *(const bf16x8*)(Kg);
  bf16x8 kv1 = *(const bf16x8*)(Kg + (size_t)32 * Kst);
  bf16x8 vv0 = *(const bf16x8*)(Vg);
  bf16x8 vv1 = *(const bf16x8*)(Vg + (size_t)32 * 32768);

  for (int kt = 0; kt < 64; kt++) {
    __syncthreads();  // prior iter's Ks/Vs/Ps reads complete
    *(bf16x8*)(Ks + tid * 8) = kv0;
    *(bf16x8*)(Ks + 32 * 64 + tid * 8) = kv1;
    *(bf16x8*)(Vs + tid * 8) = vv0;
    *(bf16x8*)(Vs + 32 * 64 + tid * 8) = vv1;
    __syncthreads();  // staged tile visible
    if (kt < 63) {    // issue next tile's loads; latency hides behind compute
      const size_t ko = (size_t)(kt + 1) * 64;
      kv0 = *(const bf16x8*)(Kg + ko * Kst);
      kv1 = *(const bf16x8*)(Kg + (ko + 32) * Kst);
      vv0 = *(const bf16x8*)(Vg + ko);
      vv1 = *(const bf16x8*)(Vg + ko + (size_t)32 * 32768);
    }

    // S = Q K^T : B-frag [k=dim][n=key] from Ks[key][dim]
    f32x4 s[4];
#pragma unroll
    for (int nt = 0; nt < 4; nt++) {
      const int key = nt * 16 + l16;
      const bf16x8 kf0 = *(const bf16x8*)(Ks + key * 64 + ((quad ^ (key & 7)) * 8));
      const bf16x8 kf1 = *(const bf16x8*)(Ks + key * 64 + (((quad + 4) ^ (key & 7)) * 8));
      f32x4 z = {0.f, 0.f, 0.f, 0.f};
      z = mfma16(qf0, kf0, z);
      s[nt] = mfma16(qf1, kf1, z);
    }

    // online softmax; row r of this quad = quad*4+r, spread over 16 lanes
    float mnew[4], alpha[4], rsum[4];
#pragma unroll
    for (int r = 0; r < 4; r++) {
      float mx = fmaxf(fmaxf(s[0][r], s[1][r]), fmaxf(s[2][r], s[3][r]));
      mx = fmaxf(mx, __shfl_xor(mx, 1));
      mx = fmaxf(mx, __shfl_xor(mx, 2));
      mx = fmaxf(mx, __shfl_xor(mx, 4));
      mx = fmaxf(mx, __shfl_xor(mx, 8));
      mnew[r] = fmaxf(mrow[r], mx);
      alpha[r] = exp2f((mrow[r] - mnew[r]) * L2E);
      rsum[r] = 0.f;
    }
#pragma unroll
    for (int nt = 0; nt < 4; nt++) {
      const int key = nt * 16 + l16;
#pragma unroll
      for (int r = 0; r < 4; r++) {
        const float p = exp2f((s[nt][r] - mnew[r]) * L2E);
        rsum[r] += p;
        const int q = quad * 4 + r;
        Ps[w][q * 64 + (((key >> 3) ^ (q & 7)) * 8) + (key & 7)] = (bf16_t)p;
      }
    }
#pragma unroll
    for (int r = 0; r < 4; r++) {
      rsum[r] += __shfl_xor(rsum[r], 1);
      rsum[r] += __shfl_xor(rsum[r], 2);
      rsum[r] += __shfl_xor(rsum[r], 4);
      rsum[r] += __shfl_xor(rsum[r], 8);
      lrow[r] = lrow[r] * alpha[r] + rsum[r];
      mrow[r] = mnew[r];
    }
#pragma unroll
    for (int nt = 0; nt < 4; nt++) {
      o[nt][0] *= alpha[0]; o[nt][1] *= alpha[1];
      o[nt][2] *= alpha[2]; o[nt][3] *= alpha[3];
    }

    __syncthreads();  // Ps visible

    const bf16x8 pf0 = *(const bf16x8*)(&Ps[w][l16 * 64 + ((quad ^ (l16 & 7)) * 8)]);
    const bf16x8 pf1 = *(const bf16x8*)(&Ps[w][l16 * 64 + (((quad + 4) ^ (l16 & 7)) * 8)]);
#pragma unroll
    for (int nt = 0; nt < 4; nt++) {
      const int d = nt * 16 + l16;
      const bf16x8 vf0 = *(const bf16x8*)(Vs + d * 64 + ((quad ^ (d & 7)) * 8));
      const bf16x8 vf1 = *(const bf16x8*)(Vs + d * 64 + (((quad + 4) ^ (d & 7)) * 8));
      o[nt] = mfma16(pf0, vf0, o[nt]);
      o[nt] = mfma16(pf1, vf1, o[nt]);
    }
  }

  float inv[4];
#pragma unroll
  for (int r = 0; r < 4; r++) inv[r] = 1.0f / fmaxf(lrow[r], 1e-30f);
#pragma unroll
  for (int nt = 0; nt < 4; nt++) {
#pragma unroll
    for (int r = 0; r < 4; r++) {
      const int row = b * 256 + qt * 64 + w * 16 + quad * 4 + r;
      QU[(size_t)row * 1024 + h * 64 + nt * 16 + l16] = (bf16_t)(o[nt][r] * inv[r]);
    }
  }
}

__global__ __launch_bounds__(256) void norm_concat(
    const float* __restrict__ E, const float* __restrict__ P,
    float* __restrict__ out) {
  const int row = blockIdx.x, tid = threadIdx.x;
  const int w = tid >> 6, lane = tid & 63;

  *(float4*)(out + (size_t)row * 2048 + tid * 4) =
      *(const float4*)(E + (size_t)row * 1024 + tid * 4);

  const float4 p = *(const float4*)(P + (size_t)row * 1024 + tid * 4);
  float ss = p.x * p.x + p.y * p.y + p.z * p.z + p.w * p.w;
#pragma unroll
  for (int m = 1; m <= 32; m <<= 1) ss += __shfl_xor(ss, m);
  __shared__ float red[4];
  if (lane == 0) red[w] = ss;
  __syncthreads();
  const float rn = rsqrtf(fmaxf(red[0] + red[1] + red[2] + red[3], 1e-30f));
  float4 q;
  q.x = p.x * rn; q.y = p.y * rn; q.z = p.z * rn; q.w = p.w * rn;
  *(float4*)(out + (size_t)row * 2048 + 1024 + tid * 4) = q;
}

extern "C" void kernel_launch(void* const* d_in, const int* in_sizes, int n_in,
                              void* d_out, int out_size, void* d_ws, size_t ws_size,
                              hipStream_t stream) {
  (void)in_sizes; (void)n_in; (void)out_size;
  const float* E   = (const float*)d_in[0];
  const float* I   = (const float*)d_in[1];
  const float* q_w = (const float*)d_in[2];
  const float* q_b = (const float*)d_in[3];
  const float* k_w = (const float*)d_in[4];
  const float* k_b = (const float*)d_in[5];
  const float* v_w = (const float*)d_in[6];
  const float* v_b = (const float*)d_in[7];
  const float* p_w = (const float*)d_in[8];
  const float* p_b = (const float*)d_in[9];
  float* out = (float*)d_out;
  char* ws = (char*)d_ws;

  if (ws_size >= (200ull << 20)) {
    // Fast path: bf16 conversions + m97 async GEMMs, all 16 heads at once.
    bf16_t* QU    = (bf16_t*)(ws);                 //   4 MB
    bf16_t* k_wbf = (bf16_t*)(ws + (4u << 20));    //   2 MB
    bf16_t* v_wbf = (bf16_t*)(ws + (6u << 20));    //   2 MB
    bf16_t* Ibf   = (bf16_t*)(ws + (8u << 20));    //  64 MB
    bf16_t* Kbuf  = (bf16_t*)(ws + (72u << 20));   //  64 MB
    bf16_t* Vtbuf = (bf16_t*)(ws + (136u << 20));  //  64 MB -> 200 MB total
    float*  Pf    = (float*)(ws + (8u << 20));     //   8 MB, overlays dead Ibf

    cvt_f32_bf16<<<16384, 256, 0, stream>>>(I, Ibf, 32768 * 1024 / 8);
    cvt_f32_bf16<<<512, 256, 0, stream>>>(k_w, k_wbf, 1024 * 1024 / 8);
    cvt_f32_bf16<<<512, 256, 0, stream>>>(v_w, v_wbf, 1024 * 1024 / 8);

    gemm_bt_reg<0, float, float><<<dim3(16, 8), 256, 0, stream>>>(
        E, q_w, q_b, QU, 2048, 1024, 1024);
    gemm_bt_async<0><<<dim3(256, 8), 256, 0, stream>>>(
        Ibf, k_wbf, k_b, Kbuf, 32768, 1024, 1024);
    gemm_bt_async<1><<<dim3(8, 256), 256, 0, stream>>>(
        v_wbf, Ibf, v_b, Vtbuf, 1024, 32768, 1024);
    attn_kernel<<<512, 256, 0, stream>>>(QU, Kbuf, Vtbuf, 0, 16, 1024);
    gemm_bt_reg<2, bf16_t, float><<<dim3(16, 8), 256, 0, stream>>>(
        QU, p_w, p_b, Pf, 2048, 1024, 1024);
    norm_concat<<<2048, 256, 0, stream>>>(E, Pf, out);
  } else {
    // Fallback: round-3 proven register path, head groups of G (needs 4+8G MB).
    int G = 2;
    if (ws_size >= (133ull << 20)) G = 16;
    else if (ws_size >= (69ull << 20)) G = 8;
    else if (ws_size >= (37ull << 20)) G = 4;
    bf16_t* QU    = (bf16_t*)(ws);                              // 4 MB
    bf16_t* Kbuf  = (bf16_t*)(ws + (4u << 20));                 // G*4 MB
    bf16_t* Vtbuf = (bf16_t*)(ws + (4u << 20) + ((size_t)G << 22));
    float*  Pf    = (float*)(ws + (4u << 20));                  // overlays Kbuf

    gemm_bt_reg<0, float, float><<<dim3(16, 8), 256, 0, stream>>>(
        E, q_w, q_b, QU, 2048, 1024, 1024);
    for (int hg = 0; hg < 16; hg += G) {
      const int Nh = G * 64;
      gemm_bt_reg<0, float, float><<<dim3(256, Nh / 128), 256, 0, stream>>>(
          I, k_w + (size_t)hg * 64 * 1024, k_b + hg * 64, Kbuf, 32768, Nh, 1024);
      gemm_bt_reg<1, float, float><<<dim3(Nh / 128, 256), 256, 0, stream>>>(
          v_w + (size_t)hg * 64 * 1024, I, v_b + hg * 64, Vtbuf, Nh, 32768, 1024);
      attn_kernel<<<32 * G, 256, 0, stream>>>(QU, Kbuf, Vtbuf, hg, G, Nh);
    }
    gemm_bt_reg<2, bf16_t, float><<<dim3(16, 8), 256, 0, stream>>>(
        QU, p_w, p_b, Pf, 2048, 1024, 1024);
    norm_concat<<<2048, 256, 0, stream>>>(E, Pf, out);
  }
}

// Round 5
// 620.545 us; speedup vs baseline: 1.2378x; 1.0331x over previous
//
#include <hip/hip_runtime.h>
#include <hip/hip_bf16.h>
#include <stdint.h>

// ContextEmbedding (f32 I/O): Q/K/V proj -> 16-head cross-attention
// (N1=256 q, N2=4096 kv, d=64) -> P proj -> L2-normalize -> concat([E, U]).
//
// Round 5: attention rewritten as S^T formulation + 4-way key split.
//  - S^T = mfma(K-frag, Q-frag): all 16 scores of a Q-row land in ONE lane
//    (C-layout col=l16=qrow) -> softmax is in-lane + 2 shfl (was 32 shfl),
//    one m/l/alpha per lane (was 4), P^T transpose via 4 b64 LDS writes/reads
//    per wave with NO barrier (wave-private Ps, in-order DS pipe).
//  - key split s=0..3 (1024 keys each), grid 512->2048 (6 blocks/CU by LDS),
//    partials (o unnormalized, m, l) -> combine kernel.
//  - GEMM path + fallback unchanged from round 4 (proven).

typedef __bf16 bf16_t;
typedef __attribute__((ext_vector_type(8))) __bf16 bf16x8;
typedef __attribute__((ext_vector_type(4))) float f32x4;

#define DEVINL __device__ __forceinline__

DEVINL f32x4 mfma16(bf16x8 a, bf16x8 b, f32x4 c) {
  return __builtin_amdgcn_mfma_f32_16x16x32_bf16(a, b, c, 0, 0, 0);
}

DEVINL bf16x8 load8(const bf16_t* p) { return *(const bf16x8*)p; }
DEVINL bf16x8 load8(const float* p) {
  const float4 u = *(const float4*)p;
  const float4 v = *(const float4*)(p + 4);
  bf16x8 r;
  r[0] = (bf16_t)u.x; r[1] = (bf16_t)u.y; r[2] = (bf16_t)u.z; r[3] = (bf16_t)u.w;
  r[4] = (bf16_t)v.x; r[5] = (bf16_t)v.y; r[6] = (bf16_t)v.z; r[7] = (bf16_t)v.w;
  return r;
}

DEVINL uint32_t pack_bf16(float a, float b) {
  union { bf16_t h[2]; uint32_t u; } x;
  x.h[0] = (bf16_t)a; x.h[1] = (bf16_t)b;
  return x.u;
}

// async global->LDS, 16 B/lane; LDS dest = wave-uniform base + lane*16.
DEVINL void async16(const void* g, void* l) {
  typedef const __attribute__((address_space(1))) unsigned int* gp1;
  typedef __attribute__((address_space(3))) unsigned int* lp3;
  __builtin_amdgcn_global_load_lds((gp1)(uintptr_t)g,
                                   (lp3)(uint32_t)(uintptr_t)l, 16, 0, 0);
}

__global__ __launch_bounds__(256) void cvt_f32_bf16(
    const float* __restrict__ src, bf16_t* __restrict__ dst, int n8) {
  const int i = blockIdx.x * 256 + threadIdx.x;
  if (i < n8) *(bf16x8*)(dst + (size_t)i * 8) = load8(src + (size_t)i * 8);
}

// ---- m97-pattern async GEMM: C[M,N] = A[M,K] @ B[N,K]^T + bias (bf16 in).
template <int MODE>  // 0: bias[n]; 1: bias[m]
__global__ __launch_bounds__(256) void gemm_bt_async(
    const bf16_t* __restrict__ A, const bf16_t* __restrict__ B,
    const float* __restrict__ bias, bf16_t* __restrict__ C,
    int M, int N, int K) {
  __shared__ bf16_t As[128 * 32];
  __shared__ bf16_t Bs[128 * 32];
  const int tid = threadIdx.x;
  const int w = tid >> 6, lane = tid & 63, quad = lane >> 4, l16 = lane & 15;
  const int bm = blockIdx.x * 128, bn = blockIdx.y * 128;
  const int wm = (w & 1) * 64, wn = (w >> 1) * 64;
  const int srow = tid >> 2;
  const int swz = ((tid & 3) ^ (srow & 3)) * 8;

  const bf16_t* Ag0 = A + (size_t)(bm + srow) * K + swz;
  const bf16_t* Ag1 = Ag0 + (size_t)64 * K;
  const bf16_t* Bg0 = B + (size_t)(bn + srow) * K + swz;
  const bf16_t* Bg1 = Bg0 + (size_t)64 * K;
  bf16_t* Al0 = As + tid * 8;
  bf16_t* Al1 = As + 64 * 32 + tid * 8;
  bf16_t* Bl0 = Bs + tid * 8;
  bf16_t* Bl1 = Bs + 64 * 32 + tid * 8;

  f32x4 acc[4][4] = {};

  for (int k0 = 0; k0 < K; k0 += 32) {
    async16(Ag0 + k0, Al0);
    async16(Ag1 + k0, Al1);
    async16(Bg0 + k0, Bl0);
    async16(Bg1 + k0, Bl1);
    __syncthreads();
    bf16x8 af[4], bfr[4];
#pragma unroll
    for (int mt = 0; mt < 4; mt++) {
      const int r = wm + mt * 16 + l16;
      af[mt] = *(const bf16x8*)(As + r * 32 + ((quad ^ (r & 3)) * 8));
    }
#pragma unroll
    for (int nt = 0; nt < 4; nt++) {
      const int r = wn + nt * 16 + l16;
      bfr[nt] = *(const bf16x8*)(Bs + r * 32 + ((quad ^ (r & 3)) * 8));
    }
#pragma unroll
    for (int mt = 0; mt < 4; mt++)
#pragma unroll
      for (int nt = 0; nt < 4; nt++)
        acc[mt][nt] = mfma16(af[mt], bfr[nt], acc[mt][nt]);
    __syncthreads();
  }

#pragma unroll
  for (int mt = 0; mt < 4; mt++) {
#pragma unroll
    for (int nt = 0; nt < 4; nt++) {
      const int gm0 = bm + wm + mt * 16 + quad * 4;
      const int gn = bn + wn + nt * 16 + l16;
#pragma unroll
      for (int r = 0; r < 4; r++) {
        const int gm = gm0 + r;
        C[(size_t)gm * N + gn] =
            (bf16_t)(acc[mt][nt][r] + bias[MODE == 1 ? gm : gn]);
      }
    }
  }
}

// ---- register-staged GEMM (small GEMMs + fallback).
template <int MODE, typename TA, typename TB>  // 2: f32 out, bias[n]
__global__ __launch_bounds__(256) void gemm_bt_reg(
    const TA* __restrict__ A, const TB* __restrict__ B,
    const float* __restrict__ bias, void* __restrict__ Cv,
    int M, int N, int K) {
  __shared__ bf16_t As[128 * 32];
  __shared__ bf16_t Bs[128 * 32];
  const int tid = threadIdx.x;
  const int w = tid >> 6, lane = tid & 63, quad = lane >> 4, l16 = lane & 15;
  const int bm = blockIdx.x * 128, bn = blockIdx.y * 128;
  const int wm = (w & 1) * 64, wn = (w >> 1) * 64;
  const int srow = tid >> 2;
  const int swz = ((tid & 3) ^ (srow & 3)) * 8;

  const TA* Ag0 = A + (size_t)(bm + srow) * K + swz;
  const TA* Ag1 = Ag0 + (size_t)64 * K;
  const TB* Bg0 = B + (size_t)(bn + srow) * K + swz;
  const TB* Bg1 = Bg0 + (size_t)64 * K;
  bf16_t* Al0 = As + tid * 8;
  bf16_t* Al1 = As + 64 * 32 + tid * 8;
  bf16_t* Bl0 = Bs + tid * 8;
  bf16_t* Bl1 = Bs + 64 * 32 + tid * 8;

  f32x4 acc[4][4] = {};

  for (int k0 = 0; k0 < K; k0 += 32) {
    const bf16x8 a0 = load8(Ag0 + k0);
    const bf16x8 a1 = load8(Ag1 + k0);
    const bf16x8 b0 = load8(Bg0 + k0);
    const bf16x8 b1 = load8(Bg1 + k0);
    *(bf16x8*)Al0 = a0;
    *(bf16x8*)Al1 = a1;
    *(bf16x8*)Bl0 = b0;
    *(bf16x8*)Bl1 = b1;
    __syncthreads();
    bf16x8 af[4], bfr[4];
#pragma unroll
    for (int mt = 0; mt < 4; mt++) {
      const int r = wm + mt * 16 + l16;
      af[mt] = *(const bf16x8*)(As + r * 32 + ((quad ^ (r & 3)) * 8));
    }
#pragma unroll
    for (int nt = 0; nt < 4; nt++) {
      const int r = wn + nt * 16 + l16;
      bfr[nt] = *(const bf16x8*)(Bs + r * 32 + ((quad ^ (r & 3)) * 8));
    }
#pragma unroll
    for (int mt = 0; mt < 4; mt++)
#pragma unroll
      for (int nt = 0; nt < 4; nt++)
        acc[mt][nt] = mfma16(af[mt], bfr[nt], acc[mt][nt]);
    __syncthreads();
  }

#pragma unroll
  for (int mt = 0; mt < 4; mt++) {
#pragma unroll
    for (int nt = 0; nt < 4; nt++) {
      const int gm0 = bm + wm + mt * 16 + quad * 4;
      const int gn = bn + wn + nt * 16 + l16;
#pragma unroll
      for (int r = 0; r < 4; r++) {
        const int gm = gm0 + r;
        float v = acc[mt][nt][r] + bias[MODE == 1 ? gm : gn];
        if (MODE == 2)
          ((float*)Cv)[(size_t)gm * N + gn] = v;
        else
          ((bf16_t*)Cv)[(size_t)gm * N + gn] = (bf16_t)v;
      }
    }
  }
}

// ---- S^T flash attention, 4-way key split.
// flat = qt*512 + s*128 + h*8 + b: qt-siblings (share K/V slice AND Q rows
// across s) are stride 512/128 apart == same id mod 8 == same XCD.
__global__ __launch_bounds__(256) void attn_split(
    const bf16_t* __restrict__ QU, const bf16_t* __restrict__ Kbuf,
    const bf16_t* __restrict__ Vtbuf, float* __restrict__ opart,
    float* __restrict__ mls) {
  __shared__ bf16_t Ks[64 * 64];     // [key][dim], 8-elem-chunk xor swizzle
  __shared__ bf16_t Vs[64 * 64];     // [dim][key], same swizzle
  __shared__ bf16_t Ps[4][16 * 64];  // per-wave P^T [qrow16][key64], 4-chunk xor
  const int tid = threadIdx.x;
  const int w = tid >> 6, lane = tid & 63, quad = lane >> 4, l16 = lane & 15;
  const int flat = blockIdx.x;
  const int qt = flat >> 9, s = (flat >> 7) & 3, h = (flat >> 3) & 15, b = flat & 7;

  // Q B-frag: B[k=dim][n=qrow]: lane n=l16=qrow, k=quad*8+j
  const int qlocal = qt * 64 + w * 16 + l16;
  const bf16_t* qbase = QU + (size_t)(b * 256 + qlocal) * 1024 + h * 64 + quad * 8;
  const bf16x8 qf0 = *(const bf16x8*)(qbase);
  const bf16x8 qf1 = *(const bf16x8*)(qbase + 32);

  const int srow = tid >> 3;
  const int swz = ((tid & 7) ^ (srow & 7)) * 8;
  const bf16_t* Kg =
      Kbuf + (size_t)(b * 4096 + s * 1024 + srow) * 1024 + h * 64 + swz;
  const bf16_t* Vg =
      Vtbuf + (size_t)(h * 64 + srow) * 32768 + b * 4096 + s * 1024 + swz;

  f32x4 o[4] = {};               // O^T C-layout: d = dt*16+quad*4+reg, qrow=l16
  float m = -1e30f, l = 0.f;     // one row (qrow=l16) per lane
  const float L2E = 1.4426950408889634f;

  bf16x8 kv0 = *(const bf16x8*)(Kg);
  bf16x8 kv1 = *(const bf16x8*)(Kg + (size_t)32 * 1024);
  bf16x8 vv0 = *(const bf16x8*)(Vg);
  bf16x8 vv1 = *(const bf16x8*)(Vg + (size_t)32 * 32768);

  for (int kt = 0; kt < 16; kt++) {
    __syncthreads();  // prior iter's Ks/Vs reads complete
    *(bf16x8*)(Ks + tid * 8) = kv0;
    *(bf16x8*)(Ks + 32 * 64 + tid * 8) = kv1;
    *(bf16x8*)(Vs + tid * 8) = vv0;
    *(bf16x8*)(Vs + 32 * 64 + tid * 8) = vv1;
    __syncthreads();  // staged tile visible
    if (kt < 15) {
      const size_t ko = (size_t)(kt + 1) * 64;
      kv0 = *(const bf16x8*)(Kg + ko * 1024);
      kv1 = *(const bf16x8*)(Kg + (ko + 32) * 1024);
      vv0 = *(const bf16x8*)(Vg + ko);
      vv1 = *(const bf16x8*)(Vg + ko + (size_t)32 * 32768);
    }

    // S^T tile [key16 x qrow16] = mfma(A=K-frag(m=key), B=Q-frag(n=qrow))
    f32x4 st[4];
#pragma unroll
    for (int nt = 0; nt < 4; nt++) {
      const int key = nt * 16 + l16;
      const bf16x8 kf0 = *(const bf16x8*)(Ks + key * 64 + ((quad ^ (key & 7)) * 8));
      const bf16x8 kf1 = *(const bf16x8*)(Ks + key * 64 + (((quad + 4) ^ (key & 7)) * 8));
      f32x4 z = {0.f, 0.f, 0.f, 0.f};
      z = mfma16(kf0, qf0, z);
      st[nt] = mfma16(kf1, qf1, z);
    }

    // lane holds 16 scores of row qrow=l16: keys nt*16 + quad*4 + reg
    float mx = st[0][0];
#pragma unroll
    for (int nt = 0; nt < 4; nt++)
#pragma unroll
      for (int r = 0; r < 4; r++) mx = fmaxf(mx, st[nt][r]);
    mx = fmaxf(mx, __shfl_xor(mx, 16));
    mx = fmaxf(mx, __shfl_xor(mx, 32));
    const float mnew = fmaxf(m, mx);
    const float alpha = exp2f((m - mnew) * L2E);

    // P^T pack + per-wave LDS write: chunk c = nt*4+quad (4 keys), phys c^l16
    float rs = 0.f;
#pragma unroll
    for (int nt = 0; nt < 4; nt++) {
      const float p0 = exp2f((st[nt][0] - mnew) * L2E);
      const float p1 = exp2f((st[nt][1] - mnew) * L2E);
      const float p2 = exp2f((st[nt][2] - mnew) * L2E);
      const float p3 = exp2f((st[nt][3] - mnew) * L2E);
      rs += (p0 + p1) + (p2 + p3);
      uint2 pkv;
      pkv.x = pack_bf16(p0, p1);
      pkv.y = pack_bf16(p2, p3);
      *(uint2*)(&Ps[w][l16 * 64 + (((nt * 4 + quad) ^ l16) * 4)]) = pkv;
    }
    rs += __shfl_xor(rs, 16);
    rs += __shfl_xor(rs, 32);
    l = l * alpha + rs;
    m = mnew;
#pragma unroll
    for (int dt = 0; dt < 4; dt++) {
      o[dt][0] *= alpha; o[dt][1] *= alpha;
      o[dt][2] *= alpha; o[dt][3] *= alpha;
    }

    // Ps is wave-private: same-wave DS ordering suffices, no barrier.
    // O^T += mfma(A=V^T-frag(m=d), B=P^T-frag(n=qrow)) over 2 key-chunks
#pragma unroll
    for (int ck = 0; ck < 2; ck++) {
      const int c0 = ck * 8 + quad * 2;  // chunks c0, c0+1 = keys quad*8..+7
      union { uint2 ab[2]; bf16x8 v; } pf;
      pf.ab[0] = *(const uint2*)(&Ps[w][l16 * 64 + ((c0 ^ l16) * 4)]);
      pf.ab[1] = *(const uint2*)(&Ps[w][l16 * 64 + (((c0 + 1) ^ l16) * 4)]);
#pragma unroll
      for (int dt = 0; dt < 4; dt++) {
        const int row = dt * 16 + l16;
        const bf16x8 vf = *(const bf16x8*)(
            Vs + row * 64 + (((ck * 4 + quad) ^ (row & 7)) * 8));
        o[dt] = mfma16(vf, pf.v, o[dt]);
      }
    }
  }

  const int pr = ((b * 16 + h) << 8) | qlocal;
  if (quad == 0) {
    mls[((size_t)s * 32768 + pr) * 2 + 0] = m;
    mls[((size_t)s * 32768 + pr) * 2 + 1] = l;
  }
#pragma unroll
  for (int dt = 0; dt < 4; dt++)
    *(f32x4*)(opart + ((size_t)s * 32768 + pr) * 64 + dt * 16 + quad * 4) = o[dt];
}

__global__ __launch_bounds__(256) void attn_combine(
    const float* __restrict__ opart, const float* __restrict__ mls,
    bf16_t* __restrict__ QU) {
  const int w = threadIdx.x >> 6, lane = threadIdx.x & 63;
  const int pr = blockIdx.x * 4 + w;
  const float L2E = 1.4426950408889634f;
  float ms[4], ls[4];
#pragma unroll
  for (int s = 0; s < 4; s++) {
    ms[s] = mls[((size_t)s * 32768 + pr) * 2 + 0];
    ls[s] = mls[((size_t)s * 32768 + pr) * 2 + 1];
  }
  const float M = fmaxf(fmaxf(ms[0], ms[1]), fmaxf(ms[2], ms[3]));
  float L = 0.f, acc = 0.f;
#pragma unroll
  for (int s = 0; s < 4; s++) {
    const float e = exp2f((ms[s] - M) * L2E);
    L += ls[s] * e;
    acc += e * opart[((size_t)s * 32768 + pr) * 64 + lane];
  }
  const int b = pr >> 12, h = (pr >> 8) & 15, q = pr & 255;
  QU[(size_t)(b * 256 + q) * 1024 + h * 64 + lane] =
      (bf16_t)(acc / fmaxf(L, 1e-30f));
}

// ---- round-4 proven attention (fallback path only).
__global__ __launch_bounds__(256) void attn_old(
    bf16_t* QU, const bf16_t* __restrict__ Kbuf,
    const bf16_t* __restrict__ Vtbuf, int hg, int G, int Kst) {
  __shared__ bf16_t Ks[64 * 64];
  __shared__ bf16_t Vs[64 * 64];
  __shared__ bf16_t Ps[4][16 * 64];
  const int tid = threadIdx.x;
  const int w = tid >> 6, lane = tid & 63, quad = lane >> 4, l16 = lane & 15;
  const int flat = blockIdx.x;
  const int qt = flat / (8 * G);
  const int rem = flat - qt * 8 * G;
  const int hh = rem % G, b = rem / G;
  const int h = hg + hh;

  const int qrow = b * 256 + qt * 64 + w * 16 + l16;
  const bf16_t* qbase = QU + (size_t)qrow * 1024 + h * 64 + quad * 8;
  const bf16x8 qf0 = *(const bf16x8*)(qbase);
  const bf16x8 qf1 = *(const bf16x8*)(qbase + 32);

  const int srow = tid >> 3;
  const int swz = ((tid & 7) ^ (srow & 7)) * 8;
  const bf16_t* Kg = Kbuf + (size_t)(b * 4096 + srow) * Kst + hh * 64 + swz;
  const bf16_t* Vg = Vtbuf + (size_t)(hh * 64 + srow) * 32768 + b * 4096 + swz;

  f32x4 o[4] = {};
  float mrow[4] = {-1e30f, -1e30f, -1e30f, -1e30f};
  float lrow[4] = {0.f, 0.f, 0.f, 0.f};
  const float L2E = 1.4426950408889634f;

  bf16x8 kv0 = *(const bf16x8*)(Kg);
  bf16x8 kv1 = *(const bf16x8*)(Kg + (size_t)32 * Kst);
  bf16x8 vv0 = *(const bf16x8*)(Vg);
  bf16x8 vv1 = *(const bf16x8*)(Vg + (size_t)32 * 32768);

  for (int kt = 0; kt < 64; kt++) {
    __syncthreads();
    *(bf16x8*)(Ks + tid * 8) = kv0;
    *(bf16x8*)(Ks + 32 * 64 + tid * 8) = kv1;
    *(bf16x8*)(Vs + tid * 8) = vv0;
    *(bf16x8*)(Vs + 32 * 64 + tid * 8) = vv1;
    __syncthreads();
    if (kt < 63) {
      const size_t ko = (size_t)(kt + 1) * 64;
      kv0 = *(const bf16x8*)(Kg + ko * Kst);
      kv1 = *(const bf16x8*)(Kg + (ko + 32) * Kst);
      vv0 = *(const bf16x8*)(Vg + ko);
      vv1 = *(const bf16x8*)(Vg + ko + (size_t)32 * 32768);
    }

    f32x4 s[4];
#pragma unroll
    for (int nt = 0; nt < 4; nt++) {
      const int key = nt * 16 + l16;
      const bf16x8 kf0 = *(const bf16x8*)(Ks + key * 64 + ((quad ^ (key & 7)) * 8));
      const bf16x8 kf1 = *(const bf16x8*)(Ks + key * 64 + (((quad + 4) ^ (key & 7)) * 8));
      f32x4 z = {0.f, 0.f, 0.f, 0.f};
      z = mfma16(qf0, kf0, z);
      s[nt] = mfma16(qf1, kf1, z);
    }

    float mnew[4], alpha[4], rsum[4];
#pragma unroll
    for (int r = 0; r < 4; r++) {
      float mx = fmaxf(fmaxf(s[0][r], s[1][r]), fmaxf(s[2][r], s[3][r]));
      mx = fmaxf(mx, __shfl_xor(mx, 1));
      mx = fmaxf(mx, __shfl_xor(mx, 2));
      mx = fmaxf(mx, __shfl_xor(mx, 4));
      mx = fmaxf(mx, __shfl_xor(mx, 8));
      mnew[r] = fmaxf(mrow[r], mx);
      alpha[r] = exp2f((mrow[r] - mnew[r]) * L2E);
      rsum[r] = 0.f;
    }
#pragma unroll
    for (int nt = 0; nt < 4; nt++) {
      const int key = nt * 16 + l16;
#pragma unroll
      for (int r = 0; r < 4; r++) {
        const float p = exp2f((s[nt][r] - mnew[r]) * L2E);
        rsum[r] += p;
        const int q = quad * 4 + r;
        Ps[w][q * 64 + (((key >> 3) ^ (q & 7)) * 8) + (key & 7)] = (bf16_t)p;
      }
    }
#pragma unroll
    for (int r = 0; r < 4; r++) {
      rsum[r] += __shfl_xor(rsum[r], 1);
      rsum[r] += __shfl_xor(rsum[r], 2);
      rsum[r] += __shfl_xor(rsum[r], 4);
      rsum[r] += __shfl_xor(rsum[r], 8);
      lrow[r] = lrow[r] * alpha[r] + rsum[r];
      mrow[r] = mnew[r];
    }
#pragma unroll
    for (int nt = 0; nt < 4; nt++) {
      o[nt][0] *= alpha[0]; o[nt][1] *= alpha[1];
      o[nt][2] *= alpha[2]; o[nt][3] *= alpha[3];
    }

    __syncthreads();

    const bf16x8 pf0 = *(const bf16x8*)(&Ps[w][l16 * 64 + ((quad ^ (l16 & 7)) * 8)]);
    const bf16x8 pf1 = *(const bf16x8*)(&Ps[w][l16 * 64 + (((quad + 4) ^ (l16 & 7)) * 8)]);
#pragma unroll
    for (int nt = 0; nt < 4; nt++) {
      const int d = nt * 16 + l16;
      const bf16x8 vf0 = *(const bf16x8*)(Vs + d * 64 + ((quad ^ (d & 7)) * 8));
      const bf16x8 vf1 = *(const bf16x8*)(Vs + d * 64 + (((quad + 4) ^ (d & 7)) * 8));
      o[nt] = mfma16(pf0, vf0, o[nt]);
      o[nt] = mfma16(pf1, vf1, o[nt]);
    }
  }

  float inv[4];
#pragma unroll
  for (int r = 0; r < 4; r++) inv[r] = 1.0f / fmaxf(lrow[r], 1e-30f);
#pragma unroll
  for (int nt = 0; nt < 4; nt++) {
#pragma unroll
    for (int r = 0; r < 4; r++) {
      const int row = b * 256 + qt * 64 + w * 16 + quad * 4 + r;
      QU[(size_t)row * 1024 + h * 64 + nt * 16 + l16] = (bf16_t)(o[nt][r] * inv[r]);
    }
  }
}

__global__ __launch_bounds__(256) void norm_concat(
    const float* __restrict__ E, const float* __restrict__ P,
    float* __restrict__ out) {
  const int row = blockIdx.x, tid = threadIdx.x;
  const int w = tid >> 6, lane = tid & 63;

  *(float4*)(out + (size_t)row * 2048 + tid * 4) =
      *(const float4*)(E + (size_t)row * 1024 + tid * 4);

  const float4 p = *(const float4*)(P + (size_t)row * 1024 + tid * 4);
  float ss = p.x * p.x + p.y * p.y + p.z * p.z + p.w * p.w;
#pragma unroll
  for (int m = 1; m <= 32; m <<= 1) ss += __shfl_xor(ss, m);
  __shared__ float red[4];
  if (lane == 0) red[w] = ss;
  __syncthreads();
  const float rn = rsqrtf(fmaxf(red[0] + red[1] + red[2] + red[3], 1e-30f));
  float4 q;
  q.x = p.x * rn; q.y = p.y * rn; q.z = p.z * rn; q.w = p.w * rn;
  *(float4*)(out + (size_t)row * 2048 + 1024 + tid * 4) = q;
}

extern "C" void kernel_launch(void* const* d_in, const int* in_sizes, int n_in,
                              void* d_out, int out_size, void* d_ws, size_t ws_size,
                              hipStream_t stream) {
  (void)in_sizes; (void)n_in; (void)out_size;
  const float* E   = (const float*)d_in[0];
  const float* I   = (const float*)d_in[1];
  const float* q_w = (const float*)d_in[2];
  const float* q_b = (const float*)d_in[3];
  const float* k_w = (const float*)d_in[4];
  const float* k_b = (const float*)d_in[5];
  const float* v_w = (const float*)d_in[6];
  const float* v_b = (const float*)d_in[7];
  const float* p_w = (const float*)d_in[8];
  const float* p_b = (const float*)d_in[9];
  float* out = (float*)d_out;
  char* ws = (char*)d_ws;

  if (ws_size >= (200ull << 20)) {
    bf16_t* QU    = (bf16_t*)(ws);                 //   4 MB
    bf16_t* k_wbf = (bf16_t*)(ws + (4u << 20));    //   2 MB
    bf16_t* v_wbf = (bf16_t*)(ws + (6u << 20));    //   2 MB
    bf16_t* Ibf   = (bf16_t*)(ws + (8u << 20));    //  64 MB (dead after GEMMs)
    float*  Pf    = (float*)(ws + (8u << 20));     //   8 MB overlays dead Ibf
    float*  opart = (float*)(ws + (16u << 20));    //  33.6 MB overlays dead Ibf
    float*  mls   = (float*)(ws + (52u << 20));    //   1 MB overlays dead Ibf
    bf16_t* Kbuf  = (bf16_t*)(ws + (72u << 20));   //  64 MB
    bf16_t* Vtbuf = (bf16_t*)(ws + (136u << 20));  //  64 MB -> 200 MB

    cvt_f32_bf16<<<16384, 256, 0, stream>>>(I, Ibf, 32768 * 1024 / 8);
    cvt_f32_bf16<<<512, 256, 0, stream>>>(k_w, k_wbf, 1024 * 1024 / 8);
    cvt_f32_bf16<<<512, 256, 0, stream>>>(v_w, v_wbf, 1024 * 1024 / 8);

    gemm_bt_reg<0, float, float><<<dim3(16, 8), 256, 0, stream>>>(
        E, q_w, q_b, QU, 2048, 1024, 1024);
    gemm_bt_async<0><<<dim3(256, 8), 256, 0, stream>>>(
        Ibf, k_wbf, k_b, Kbuf, 32768, 1024, 1024);
    gemm_bt_async<1><<<dim3(8, 256), 256, 0, stream>>>(
        v_wbf, Ibf, v_b, Vtbuf, 1024, 32768, 1024);
    attn_split<<<2048, 256, 0, stream>>>(QU, Kbuf, Vtbuf, opart, mls);
    attn_combine<<<8192, 256, 0, stream>>>(opart, mls, QU);
    gemm_bt_reg<2, bf16_t, float><<<dim3(16, 8), 256, 0, stream>>>(
        QU, p_w, p_b, Pf, 2048, 1024, 1024);
    norm_concat<<<2048, 256, 0, stream>>>(E, Pf, out);
  } else {
    // Fallback: round-4 proven register path, head groups of G (needs 4+8G MB).
    int G = 2;
    if (ws_size >= (133ull << 20)) G = 16;
    else if (ws_size >= (69ull << 20)) G = 8;
    else if (ws_size >= (37ull << 20)) G = 4;
    bf16_t* QU    = (bf16_t*)(ws);
    bf16_t* Kbuf  = (bf16_t*)(ws + (4u << 20));
    bf16_t* Vtbuf = (bf16_t*)(ws + (4u << 20) + ((size_t)G << 22));
    float*  Pf    = (float*)(ws + (4u << 20));

    gemm_bt_reg<0, float, float><<<dim3(16, 8), 256, 0, stream>>>(
        E, q_w, q_b, QU, 2048, 1024, 1024);
    for (int hg = 0; hg < 16; hg += G) {
      const int Nh = G * 64;
      gemm_bt_reg<0, float, float><<<dim3(256, Nh / 128), 256, 0, stream>>>(
          I, k_w + (size_t)hg * 64 * 1024, k_b + hg * 64, Kbuf, 32768, Nh, 1024);
      gemm_bt_reg<1, float, float><<<dim3(Nh / 128, 256), 256, 0, stream>>>(
          v_w + (size_t)hg * 64 * 1024, I, v_b + hg * 64, Vtbuf, Nh, 32768, 1024);
      attn_old<<<32 * G, 256, 0, stream>>>(QU, Kbuf, Vtbuf, hg, G, Nh);
    }
    gemm_bt_reg<2, bf16_t, float><<<dim3(16, 8), 256, 0, stream>>>(
        QU, p_w, p_b, Pf, 2048, 1024, 1024);
    norm_concat<<<2048, 256, 0, stream>>>(E, Pf, out);
  }
}